// Round 1
// baseline (309.058 us; speedup 1.0000x reference)
//
#include <hip/hip_runtime.h>
#include <stdint.h>

#define NB 32
#define NN 25200
#define TOPK 1024
#define NF 16
#define CONF 0.25f
#define IOU_T 0.45f

// monotone-ascending uint32 map of the reference's s = valid ? obj*cls : -1.0
__device__ __forceinline__ uint32_t score_key(float obj, float cls) {
  float score = __fmul_rn(cls, obj);
  bool valid = (obj > CONF) && (score > CONF);
  float s = valid ? score : -1.0f;
  uint32_t u = __float_as_uint(s);
  return (u & 0x80000000u) ? ~u : (u | 0x80000000u);
}

__global__ void k_keys(const float* __restrict__ pred, uint32_t* __restrict__ keys) {
  int g = blockIdx.x * blockDim.x + threadIdx.x;
  if (g >= NB * NN) return;
  const float* row = pred + (size_t)g * NF;
  keys[g] = score_key(row[4], row[15]);
}

// One block per image: 8-pass radix descent over 64-bit key = (key32<<32)|~n
// (all distinct), exact rank-1024 cutoff, compact >=cut (exactly 1024),
// bitonic sort ascending, write selected indices in top_k order.
__global__ __launch_bounds__(1024) void k_select(const uint32_t* __restrict__ keys,
                                                 int* __restrict__ sel) {
  int b = blockIdx.x;
  int tid = threadIdx.x;
  const uint32_t* kb = keys + (size_t)b * NN;
  __shared__ uint32_t hist[256];
  __shared__ uint64_t sh_prefix;
  __shared__ uint32_t sh_rank;
  __shared__ uint32_t sh_cnt;
  __shared__ uint64_t ent[TOPK];
  if (tid == 0) { sh_prefix = 0; sh_rank = TOPK; sh_cnt = 0; }
  ent[tid] = 0;
  __syncthreads();

  for (int shift = 56; shift >= 0; shift -= 8) {
    if (tid < 256) hist[tid] = 0;
    __syncthreads();
    uint64_t pfx = sh_prefix;
    for (int n = tid; n < NN; n += 1024) {
      uint64_t k64 = ((uint64_t)kb[n] << 32) | (uint32_t)(~(uint32_t)n);
      bool match = (shift == 56) || ((k64 >> (shift + 8)) == (pfx >> (shift + 8)));
      if (match) atomicAdd(&hist[(uint32_t)(k64 >> shift) & 255u], 1u);
    }
    __syncthreads();
    if (tid == 0) {
      uint32_t r = sh_rank;
      uint64_t p = sh_prefix;
      for (int bin = 255; bin >= 0; --bin) {
        uint32_t c = hist[bin];
        if (c >= r) { sh_prefix = p | ((uint64_t)bin << shift); break; }
        r -= c;
      }
      sh_rank = r;
    }
    __syncthreads();
  }

  uint64_t cut = sh_prefix;
  for (int n = tid; n < NN; n += 1024) {
    uint64_t k64 = ((uint64_t)kb[n] << 32) | (uint32_t)(~(uint32_t)n);
    if (k64 >= cut) {
      uint32_t p = atomicAdd(&sh_cnt, 1u);
      if (p < TOPK) ent[p] = k64;
    }
  }
  __syncthreads();

  // bitonic sort ascending, 1 elem/thread
  for (unsigned kk = 2; kk <= TOPK; kk <<= 1) {
    for (unsigned j = kk >> 1; j > 0; j >>= 1) {
      unsigned ixj = (unsigned)tid ^ j;
      if (ixj > (unsigned)tid) {
        uint64_t a = ent[tid], c = ent[ixj];
        bool up = ((tid & kk) == 0);
        if (up ? (a > c) : (a < c)) { ent[tid] = c; ent[ixj] = a; }
      }
      __syncthreads();
    }
  }
  uint32_t nsel = ~(uint32_t)(ent[tid] & 0xFFFFFFFFu);
  if (nsel >= NN) nsel = 0;  // safety only
  sel[(size_t)b * TOPK + (TOPK - 1 - tid)] = (int)nsel;
}

// grid (NB, 8): block handles 128 rows of one image's 1024x1024 IoU>thres
// bitmask (upper-triangular: bit j set only for j>i). Layout column-major:
// mask[b][word][row] so writes here and per-lane streaming reads in the scan
// are both friendly. tid = part*128 + r_local; part owns 128 j's (4 words).
__global__ __launch_bounds__(1024) void k_mask(const float* __restrict__ pred,
                                               const int* __restrict__ sel,
                                               uint32_t* __restrict__ mask) {
  int b = blockIdx.x;
  int sblk = blockIdx.y;
  int tid = threadIdx.x;
  __shared__ float bx1[TOPK], by1[TOPK], bx2[TOPK], by2[TOPK], bar[TOPK];
  {
    int n = sel[(size_t)b * TOPK + tid];
    const float* row = pred + ((size_t)b * NN + n) * NF;
    float cx = row[0], cy = row[1], w = row[2], h = row[3];
    float hw = __fmul_rn(w, 0.5f), hh = __fmul_rn(h, 0.5f);
    float x1 = __fsub_rn(cx, hw), y1 = __fsub_rn(cy, hh);
    float x2 = __fadd_rn(cx, hw), y2 = __fadd_rn(cy, hh);
    bx1[tid] = x1; by1[tid] = y1; bx2[tid] = x2; by2[tid] = y2;
    bar[tid] = __fmul_rn(__fsub_rn(x2, x1), __fsub_rn(y2, y1));
  }
  __syncthreads();
  int r_local = tid & 127;
  int part = tid >> 7;
  int i = sblk * 128 + r_local;
  float x1i = bx1[i], y1i = by1[i], x2i = bx2[i], y2i = by2[i], ai = bar[i];
  int jbase = part * 128;
  for (int wN = 0; wN < 4; ++wN) {
    uint32_t word = 0;
    int j0 = jbase + wN * 32;
    #pragma unroll
    for (int t2 = 0; t2 < 32; ++t2) {
      int j = j0 + t2;
      float lx = fmaxf(x1i, bx1[j]);
      float ly = fmaxf(y1i, by1[j]);
      float rx = fminf(x2i, bx2[j]);
      float ry = fminf(y2i, by2[j]);
      float wd = fmaxf(__fsub_rn(rx, lx), 0.0f);
      float ht = fmaxf(__fsub_rn(ry, ly), 0.0f);
      float inter = __fmul_rn(wd, ht);
      float den = __fadd_rn(__fsub_rn(__fadd_rn(ai, bar[j]), inter), 1e-7f);
      float iou = __fdiv_rn(inter, den);
      uint32_t bit = ((iou > IOU_T) && (j > i)) ? 1u : 0u;
      word |= bit << t2;
    }
    mask[(size_t)b * (32 * TOPK) + (size_t)(part * 4 + wN) * TOPK + i] = word;
  }
}

// One block per image. Half-wave 0 (lanes 0..31, lane=word) runs the serial
// greedy scan with depth-16 register prefetch; then all 1024 threads write out.
__global__ __launch_bounds__(1024) void k_scan_out(const float* __restrict__ pred,
                                                   const int* __restrict__ sel,
                                                   const uint32_t* __restrict__ mask,
                                                   float* __restrict__ det,
                                                   float* __restrict__ keep_out) {
  int b = blockIdx.x;
  int tid = threadIdx.x;
  __shared__ uint32_t vbits[32];
  __shared__ uint32_t keepw[32];
  if (tid < 32) vbits[tid] = 0;
  __syncthreads();
  int n = sel[(size_t)b * TOPK + tid];
  const float* row = pred + ((size_t)b * NN + n) * NF;
  float obj = row[4], cls = row[15];
  float score = __fmul_rn(cls, obj);
  bool valid = (obj > CONF) && (score > CONF);
  if (valid) atomicOr(&vbits[tid >> 5], 1u << (tid & 31));
  __syncthreads();

  if (tid < 32) {
    int lane = tid;
    uint32_t kw = vbits[lane];
    const uint32_t* mcol = mask + (size_t)b * (32 * TOPK) + (size_t)lane * TOPK;
    uint4 c0 = *(const uint4*)(mcol + 0);
    uint4 c1 = *(const uint4*)(mcol + 4);
    uint4 c2 = *(const uint4*)(mcol + 8);
    uint4 c3 = *(const uint4*)(mcol + 12);
    for (int base = 0; base < TOPK; base += 16) {
      uint4 n0, n1, n2, n3;
      bool more = (base + 16) < TOPK;
      if (more) {
        const uint32_t* p = mcol + base + 16;
        n0 = *(const uint4*)(p);     n1 = *(const uint4*)(p + 4);
        n2 = *(const uint4*)(p + 8); n3 = *(const uint4*)(p + 12);
      }
      uint32_t cw[16] = {c0.x, c0.y, c0.z, c0.w, c1.x, c1.y, c1.z, c1.w,
                         c2.x, c2.y, c2.z, c2.w, c3.x, c3.y, c3.z, c3.w};
      #pragma unroll
      for (int t = 0; t < 16; ++t) {
        int i = base + t;
        uint32_t wv = __shfl(kw, i >> 5, 64);
        if ((wv >> (i & 31)) & 1u) kw &= ~cw[t];
      }
      if (more) { c0 = n0; c1 = n1; c2 = n2; c3 = n3; }
    }
    keepw[lane] = kw;
  }
  __syncthreads();

  bool kept = (keepw[tid >> 5] >> (tid & 31)) & 1u;
  float m = kept ? 1.0f : 0.0f;
  float cx = row[0], cy = row[1], w = row[2], h = row[3];
  float hw = __fmul_rn(w, 0.5f), hh = __fmul_rn(h, 0.5f);
  float4 o0 = make_float4(__fsub_rn(cx, hw) * m, __fsub_rn(cy, hh) * m,
                          __fadd_rn(cx, hw) * m, __fadd_rn(cy, hh) * m);
  float4 o1 = make_float4(score * m, row[5] * m, row[6] * m, row[7] * m);
  float4 o2 = make_float4(row[8] * m, row[9] * m, row[10] * m, row[11] * m);
  float4 o3 = make_float4(row[12] * m, row[13] * m, row[14] * m, 0.0f);
  float4* dst = (float4*)(det + ((size_t)b * TOPK + tid) * NF);
  dst[0] = o0; dst[1] = o1; dst[2] = o2; dst[3] = o3;
  keep_out[(size_t)b * TOPK + tid] = m;
}

extern "C" void kernel_launch(void* const* d_in, const int* in_sizes, int n_in,
                              void* d_out, int out_size, void* d_ws, size_t ws_size,
                              hipStream_t stream) {
  const float* pred = (const float*)d_in[0];
  float* det = (float*)d_out;
  float* keep = det + (size_t)NB * TOPK * NF;

  uint8_t* ws = (uint8_t*)d_ws;
  uint32_t* keys = (uint32_t*)ws;                                   // NB*NN u32 = 3,225,600 B
  int* sel = (int*)(ws + (size_t)NB * NN * 4);                      // NB*TOPK i32 = 131,072 B
  uint32_t* mask = (uint32_t*)(ws + (size_t)NB * NN * 4
                                  + (size_t)NB * TOPK * 4);         // NB*32*TOPK u32 = 4,194,304 B

  k_keys<<<(NB * NN + 255) / 256, 256, 0, stream>>>(pred, keys);
  k_select<<<NB, 1024, 0, stream>>>(keys, sel);
  dim3 gm(NB, 8);
  k_mask<<<gm, 1024, 0, stream>>>(pred, sel, mask);
  k_scan_out<<<NB, 1024, 0, stream>>>(pred, sel, mask, det, keep);
}

// Round 2
// 219.074 us; speedup vs baseline: 1.4108x; 1.4108x over previous
//
#include <hip/hip_runtime.h>
#include <stdint.h>

#define NB 32
#define NN 25200
#define TOPK 1024
#define NF 16
#define CONF 0.25f
#define IOU_T 0.45f
#define NBIN 4096
#define CAP 2048
#define INV_KEY 0x407FFFFFu   // score_key(-1.0f)

// monotone-ascending uint32 map of the reference's s = valid ? obj*cls : -1.0
__device__ __forceinline__ uint32_t score_key(float obj, float cls) {
  float score = __fmul_rn(cls, obj);
  bool valid = (obj > CONF) && (score > CONF);
  float s = valid ? score : -1.0f;
  uint32_t u = __float_as_uint(s);
  return (u & 0x80000000u) ? ~u : (u | 0x80000000u);
}

__global__ void k_keys(const float* __restrict__ pred, uint32_t* __restrict__ keys) {
  int g = blockIdx.x * blockDim.x + threadIdx.x;
  if (g >= NB * NN) return;
  const float* row = pred + (size_t)g * NF;
  keys[g] = score_key(row[4], row[15]);
}

// One block per image. 12-bit histogram over key32 -> parallel suffix-scan to
// find the bin containing rank-1024 -> compact all elements in bins >= b*
// (<= ~1650 for this distribution, CAP=2048) -> bitonic sort 2048 descending
// on 64-bit key (key32<<32 | ~n, all distinct) -> top-1024 in exact
// jax.lax.top_k order.
__global__ __launch_bounds__(1024) void k_select(const uint32_t* __restrict__ keys,
                                                 int* __restrict__ sel) {
  int b = blockIdx.x;
  int tid = threadIdx.x;
  int lane = tid & 63, wid = tid >> 6;
  const uint32_t* kb = keys + (size_t)b * NN;
  __shared__ uint32_t hist[NBIN];
  __shared__ uint64_t ent[CAP];
  __shared__ uint32_t wsum[16];
  __shared__ uint32_t sh_bin;
  __shared__ uint32_t sh_cnt;
  #pragma unroll
  for (int k = 0; k < 4; ++k) hist[tid + 1024 * k] = 0;
  ent[tid] = 0; ent[tid + 1024] = 0;
  if (tid == 0) sh_cnt = 0;
  __syncthreads();

  // phase 1: histogram; invalid keys (one degenerate value, ~15k/image)
  // aggregated per-wave via ballot to avoid the same-address atomic storm
  for (int n = tid; n < NN; n += 1024) {
    uint32_t key = kb[n];
    bool inv = (key == INV_KEY);
    uint64_t bal = __ballot(inv);
    if (lane == 0 && bal) atomicAdd(&hist[INV_KEY >> 20], (uint32_t)__popcll(bal));
    if (!inv) atomicAdd(&hist[key >> 20], 1u);
  }
  __syncthreads();

  // phase 2: descending-bin cumulative via shfl scan; find crossing bin
  uint32_t h[4]; uint32_t s = 0;
  #pragma unroll
  for (int k = 0; k < 4; ++k) { h[k] = hist[NBIN - 1 - (4 * tid + k)]; s += h[k]; }
  uint32_t my = s;
  #pragma unroll
  for (int d = 1; d < 64; d <<= 1) {
    uint32_t v = __shfl_up(s, d, 64);
    if (lane >= d) s += v;
  }
  if (lane == 63) wsum[wid] = s;
  __syncthreads();
  uint32_t base = 0;
  for (int w = 0; w < wid; ++w) base += wsum[w];
  uint32_t cum = base + s - my;  // exclusive prefix (descending bins)
  #pragma unroll
  for (int k = 0; k < 4; ++k) {
    if (cum < TOPK && cum + h[k] >= TOPK) sh_bin = (uint32_t)(NBIN - 1 - (4 * tid + k));
    cum += h[k];
  }
  __syncthreads();
  uint32_t bstar = sh_bin;

  // phase 3: compact everything in bins >= b* (contains all of top-1024)
  for (int n = tid; n < NN; n += 1024) {
    uint32_t key = kb[n];
    if ((key >> 20) >= bstar) {
      uint32_t p = atomicAdd(&sh_cnt, 1u);
      if (p < CAP) ent[p] = ((uint64_t)key << 32) | (uint32_t)(~(uint32_t)n);
    }
  }
  __syncthreads();

  // phase 4: bitonic sort CAP=2048 descending, 2 elems/thread
  for (unsigned kk = 2; kk <= CAP; kk <<= 1) {
    for (unsigned j = kk >> 1; j > 0; j >>= 1) {
      #pragma unroll
      for (int r = 0; r < 2; ++r) {
        unsigned e = (unsigned)tid + (unsigned)r * 1024u;
        unsigned ixj = e ^ j;
        if (ixj > e) {
          uint64_t a = ent[e], c = ent[ixj];
          bool up = ((e & kk) == 0);
          if (up ? (a < c) : (a > c)) { ent[e] = c; ent[ixj] = a; }
        }
      }
      __syncthreads();
    }
  }
  uint32_t n = ~(uint32_t)(ent[tid] & 0xFFFFFFFFu);
  if (n >= NN) n = 0;  // safety only (cnt >= 1024 always here)
  sel[(size_t)b * TOPK + tid] = (int)n;
}

// grid (NB, 8): block handles 128 rows of one image's 1024x1024 IoU>thres
// bitmask (upper-triangular: bit j set only for j>i). Column-major layout
// mask[b][word][row] for coalesced writes and streaming scan reads.
__global__ __launch_bounds__(1024) void k_mask(const float* __restrict__ pred,
                                               const int* __restrict__ sel,
                                               uint32_t* __restrict__ mask) {
  int b = blockIdx.x;
  int sblk = blockIdx.y;
  int tid = threadIdx.x;
  __shared__ float bx1[TOPK], by1[TOPK], bx2[TOPK], by2[TOPK], bar[TOPK];
  {
    int n = sel[(size_t)b * TOPK + tid];
    const float4* row = (const float4*)(pred + ((size_t)b * NN + n) * NF);
    float4 r0 = row[0];
    float hw = __fmul_rn(r0.z, 0.5f), hh = __fmul_rn(r0.w, 0.5f);
    float x1 = __fsub_rn(r0.x, hw), y1 = __fsub_rn(r0.y, hh);
    float x2 = __fadd_rn(r0.x, hw), y2 = __fadd_rn(r0.y, hh);
    bx1[tid] = x1; by1[tid] = y1; bx2[tid] = x2; by2[tid] = y2;
    bar[tid] = __fmul_rn(__fsub_rn(x2, x1), __fsub_rn(y2, y1));
  }
  __syncthreads();
  int r_local = tid & 127;
  int part = tid >> 7;
  int i = sblk * 128 + r_local;
  float x1i = bx1[i], y1i = by1[i], x2i = bx2[i], y2i = by2[i], ai = bar[i];
  int jbase = part * 128;
  for (int wN = 0; wN < 4; ++wN) {
    uint32_t word = 0;
    int j0 = jbase + wN * 32;
    #pragma unroll
    for (int t2 = 0; t2 < 32; ++t2) {
      int j = j0 + t2;
      float lx = fmaxf(x1i, bx1[j]);
      float ly = fmaxf(y1i, by1[j]);
      float rx = fminf(x2i, bx2[j]);
      float ry = fminf(y2i, by2[j]);
      float wd = fmaxf(__fsub_rn(rx, lx), 0.0f);
      float ht = fmaxf(__fsub_rn(ry, ly), 0.0f);
      float inter = __fmul_rn(wd, ht);
      float den = __fadd_rn(__fsub_rn(__fadd_rn(ai, bar[j]), inter), 1e-7f);
      float iou = __fdiv_rn(inter, den);
      uint32_t bit = ((iou > IOU_T) && (j > i)) ? 1u : 0u;
      word |= bit << t2;
    }
    mask[(size_t)b * (32 * TOPK) + (size_t)(part * 4 + wN) * TOPK + i] = word;
  }
}

// One block per image. Half-wave 0 (lanes 0..31, lane=word) runs the serial
// greedy scan with depth-16 register prefetch; then all 1024 threads write out.
__global__ __launch_bounds__(1024) void k_scan_out(const float* __restrict__ pred,
                                                   const int* __restrict__ sel,
                                                   const uint32_t* __restrict__ mask,
                                                   float* __restrict__ det,
                                                   float* __restrict__ keep_out) {
  int b = blockIdx.x;
  int tid = threadIdx.x;
  __shared__ uint32_t vbits[32];
  __shared__ uint32_t keepw[32];
  if (tid < 32) vbits[tid] = 0;
  __syncthreads();
  int n = sel[(size_t)b * TOPK + tid];
  const float4* rowv = (const float4*)(pred + ((size_t)b * NN + n) * NF);
  float4 r0 = rowv[0], r1 = rowv[1], r2 = rowv[2], r3 = rowv[3];
  float obj = r1.x, cls = r3.w;
  float score = __fmul_rn(cls, obj);
  bool valid = (obj > CONF) && (score > CONF);
  if (valid) atomicOr(&vbits[tid >> 5], 1u << (tid & 31));
  __syncthreads();

  if (tid < 32) {
    int lane = tid;
    uint32_t kw = vbits[lane];
    const uint32_t* mcol = mask + (size_t)b * (32 * TOPK) + (size_t)lane * TOPK;
    uint4 c0 = *(const uint4*)(mcol + 0);
    uint4 c1 = *(const uint4*)(mcol + 4);
    uint4 c2 = *(const uint4*)(mcol + 8);
    uint4 c3 = *(const uint4*)(mcol + 12);
    for (int base = 0; base < TOPK; base += 16) {
      uint4 n0, n1, n2, n3;
      bool more = (base + 16) < TOPK;
      if (more) {
        const uint32_t* p = mcol + base + 16;
        n0 = *(const uint4*)(p);     n1 = *(const uint4*)(p + 4);
        n2 = *(const uint4*)(p + 8); n3 = *(const uint4*)(p + 12);
      }
      uint32_t cw[16] = {c0.x, c0.y, c0.z, c0.w, c1.x, c1.y, c1.z, c1.w,
                         c2.x, c2.y, c2.z, c2.w, c3.x, c3.y, c3.z, c3.w};
      #pragma unroll
      for (int t = 0; t < 16; ++t) {
        int i = base + t;
        uint32_t wv = __shfl(kw, i >> 5, 64);
        if ((wv >> (i & 31)) & 1u) kw &= ~cw[t];
      }
      if (more) { c0 = n0; c1 = n1; c2 = n2; c3 = n3; }
    }
    keepw[lane] = kw;
  }
  __syncthreads();

  bool kept = (keepw[tid >> 5] >> (tid & 31)) & 1u;
  float m = kept ? 1.0f : 0.0f;
  float hw = __fmul_rn(r0.z, 0.5f), hh = __fmul_rn(r0.w, 0.5f);
  float4 o0 = make_float4(__fsub_rn(r0.x, hw) * m, __fsub_rn(r0.y, hh) * m,
                          __fadd_rn(r0.x, hw) * m, __fadd_rn(r0.y, hh) * m);
  float4 o1 = make_float4(score * m, r1.y * m, r1.z * m, r1.w * m);
  float4 o2 = make_float4(r2.x * m, r2.y * m, r2.z * m, r2.w * m);
  float4 o3 = make_float4(r3.x * m, r3.y * m, r3.z * m, 0.0f);
  float4* dst = (float4*)(det + ((size_t)b * TOPK + tid) * NF);
  dst[0] = o0; dst[1] = o1; dst[2] = o2; dst[3] = o3;
  keep_out[(size_t)b * TOPK + tid] = m;
}

extern "C" void kernel_launch(void* const* d_in, const int* in_sizes, int n_in,
                              void* d_out, int out_size, void* d_ws, size_t ws_size,
                              hipStream_t stream) {
  const float* pred = (const float*)d_in[0];
  float* det = (float*)d_out;
  float* keep = det + (size_t)NB * TOPK * NF;

  uint8_t* ws = (uint8_t*)d_ws;
  uint32_t* keys = (uint32_t*)ws;                                   // NB*NN u32
  int* sel = (int*)(ws + (size_t)NB * NN * 4);                      // NB*TOPK i32
  uint32_t* mask = (uint32_t*)(ws + (size_t)NB * NN * 4
                                  + (size_t)NB * TOPK * 4);         // NB*32*TOPK u32

  k_keys<<<(NB * NN + 255) / 256, 256, 0, stream>>>(pred, keys);
  k_select<<<NB, 1024, 0, stream>>>(keys, sel);
  dim3 gm(NB, 8);
  k_mask<<<gm, 1024, 0, stream>>>(pred, sel, mask);
  k_scan_out<<<NB, 1024, 0, stream>>>(pred, sel, mask, det, keep);
}

// Round 3
// 186.836 us; speedup vs baseline: 1.6542x; 1.1725x over previous
//
#include <hip/hip_runtime.h>
#include <stdint.h>

#define NB 32
#define NN 25200
#define TOPK 1024
#define NF 16
#define CONF 0.25f
#define IOU_T 0.45f
#define NBIN 4096
#define CAP 2048
#define INV_KEY 0x407FFFFFu   // score_key(-1.0f)

// monotone-ascending uint32 map of the reference's s = valid ? obj*cls : -1.0
__device__ __forceinline__ uint32_t score_key(float obj, float cls) {
  float score = __fmul_rn(cls, obj);
  bool valid = (obj > CONF) && (score > CONF);
  float s = valid ? score : -1.0f;
  uint32_t u = __float_as_uint(s);
  return (u & 0x80000000u) ? ~u : (u | 0x80000000u);
}

__global__ void k_keys(const float* __restrict__ pred, uint32_t* __restrict__ keys) {
  int g = blockIdx.x * blockDim.x + threadIdx.x;
  if (g >= NB * NN) return;
  const float* row = pred + (size_t)g * NF;
  keys[g] = score_key(row[4], row[15]);
}

// One block per image. 12-bit histogram over key32 -> parallel suffix-scan to
// find the bin containing rank-1024 -> compact all elements in bins >= b*
// (<= ~1650 for this distribution, CAP=2048) -> bitonic sort 2048 descending
// on 64-bit key (key32<<32 | ~n, all distinct) -> top-1024 in exact
// jax.lax.top_k order.
__global__ __launch_bounds__(1024) void k_select(const uint32_t* __restrict__ keys,
                                                 int* __restrict__ sel) {
  int b = blockIdx.x;
  int tid = threadIdx.x;
  int lane = tid & 63, wid = tid >> 6;
  const uint32_t* kb = keys + (size_t)b * NN;
  __shared__ uint32_t hist[NBIN];
  __shared__ uint64_t ent[CAP];
  __shared__ uint32_t wsum[16];
  __shared__ uint32_t sh_bin;
  __shared__ uint32_t sh_cnt;
  #pragma unroll
  for (int k = 0; k < 4; ++k) hist[tid + 1024 * k] = 0;
  ent[tid] = 0; ent[tid + 1024] = 0;
  if (tid == 0) sh_cnt = 0;
  __syncthreads();

  // phase 1: histogram; invalid keys (one degenerate value, ~15k/image)
  // aggregated per-wave via ballot to avoid the same-address atomic storm
  for (int n = tid; n < NN; n += 1024) {
    uint32_t key = kb[n];
    bool inv = (key == INV_KEY);
    uint64_t bal = __ballot(inv);
    if (lane == 0 && bal) atomicAdd(&hist[INV_KEY >> 20], (uint32_t)__popcll(bal));
    if (!inv) atomicAdd(&hist[key >> 20], 1u);
  }
  __syncthreads();

  // phase 2: descending-bin cumulative via shfl scan; find crossing bin
  uint32_t h[4]; uint32_t s = 0;
  #pragma unroll
  for (int k = 0; k < 4; ++k) { h[k] = hist[NBIN - 1 - (4 * tid + k)]; s += h[k]; }
  uint32_t my = s;
  #pragma unroll
  for (int d = 1; d < 64; d <<= 1) {
    uint32_t v = __shfl_up(s, d, 64);
    if (lane >= d) s += v;
  }
  if (lane == 63) wsum[wid] = s;
  __syncthreads();
  uint32_t base = 0;
  for (int w = 0; w < wid; ++w) base += wsum[w];
  uint32_t cum = base + s - my;  // exclusive prefix (descending bins)
  #pragma unroll
  for (int k = 0; k < 4; ++k) {
    if (cum < TOPK && cum + h[k] >= TOPK) sh_bin = (uint32_t)(NBIN - 1 - (4 * tid + k));
    cum += h[k];
  }
  __syncthreads();
  uint32_t bstar = sh_bin;

  // phase 3: compact everything in bins >= b* (contains all of top-1024)
  for (int n = tid; n < NN; n += 1024) {
    uint32_t key = kb[n];
    if ((key >> 20) >= bstar) {
      uint32_t p = atomicAdd(&sh_cnt, 1u);
      if (p < CAP) ent[p] = ((uint64_t)key << 32) | (uint32_t)(~(uint32_t)n);
    }
  }
  __syncthreads();

  // phase 4: bitonic sort CAP=2048 descending, 2 elems/thread
  for (unsigned kk = 2; kk <= CAP; kk <<= 1) {
    for (unsigned j = kk >> 1; j > 0; j >>= 1) {
      #pragma unroll
      for (int r = 0; r < 2; ++r) {
        unsigned e = (unsigned)tid + (unsigned)r * 1024u;
        unsigned ixj = e ^ j;
        if (ixj > e) {
          uint64_t a = ent[e], c = ent[ixj];
          bool up = ((e & kk) == 0);
          if (up ? (a < c) : (a > c)) { ent[e] = c; ent[ixj] = a; }
        }
      }
      __syncthreads();
    }
  }
  uint32_t n = ~(uint32_t)(ent[tid] & 0xFFFFFFFFu);
  if (n >= NN) n = 0;  // safety only (cnt >= 1024 always here)
  sel[(size_t)b * TOPK + tid] = (int)n;
}

// grid (NB, 8): block handles 128 rows of one image's 1024x1024 IoU>thres
// bitmask (upper-triangular: bit j set only for j>i). Column-major layout
// mask[b][word][row] for coalesced writes and streaming scan reads.
__global__ __launch_bounds__(1024) void k_mask(const float* __restrict__ pred,
                                               const int* __restrict__ sel,
                                               uint32_t* __restrict__ mask) {
  int b = blockIdx.x;
  int sblk = blockIdx.y;
  int tid = threadIdx.x;
  __shared__ float bx1[TOPK], by1[TOPK], bx2[TOPK], by2[TOPK], bar[TOPK];
  {
    int n = sel[(size_t)b * TOPK + tid];
    const float4* row = (const float4*)(pred + ((size_t)b * NN + n) * NF);
    float4 r0 = row[0];
    float hw = __fmul_rn(r0.z, 0.5f), hh = __fmul_rn(r0.w, 0.5f);
    float x1 = __fsub_rn(r0.x, hw), y1 = __fsub_rn(r0.y, hh);
    float x2 = __fadd_rn(r0.x, hw), y2 = __fadd_rn(r0.y, hh);
    bx1[tid] = x1; by1[tid] = y1; bx2[tid] = x2; by2[tid] = y2;
    bar[tid] = __fmul_rn(__fsub_rn(x2, x1), __fsub_rn(y2, y1));
  }
  __syncthreads();
  int r_local = tid & 127;
  int part = tid >> 7;
  int i = sblk * 128 + r_local;
  float x1i = bx1[i], y1i = by1[i], x2i = bx2[i], y2i = by2[i], ai = bar[i];
  int jbase = part * 128;
  for (int wN = 0; wN < 4; ++wN) {
    uint32_t word = 0;
    int j0 = jbase + wN * 32;
    #pragma unroll
    for (int t2 = 0; t2 < 32; ++t2) {
      int j = j0 + t2;
      float lx = fmaxf(x1i, bx1[j]);
      float ly = fmaxf(y1i, by1[j]);
      float rx = fminf(x2i, bx2[j]);
      float ry = fminf(y2i, by2[j]);
      float wd = fmaxf(__fsub_rn(rx, lx), 0.0f);
      float ht = fmaxf(__fsub_rn(ry, ly), 0.0f);
      float inter = __fmul_rn(wd, ht);
      float den = __fadd_rn(__fsub_rn(__fadd_rn(ai, bar[j]), inter), 1e-7f);
      float iou = __fdiv_rn(inter, den);
      uint32_t bit = ((iou > IOU_T) && (j > i)) ? 1u : 0u;
      word |= bit << t2;
    }
    mask[(size_t)b * (32 * TOPK) + (size_t)(part * 4 + wN) * TOPK + i] = word;
  }
}

// One block per image. Word-serial greedy scan: 32 outer iterations; lane l
// owns keep word l. Per iteration w: lanes preload their 32 mask words for
// rows 32w..32w+31 (register double-buffer, global loads overlap compute);
// lane w resolves intra-word suppression serially in ALU; one shfl broadcast;
// all lanes apply cross-word suppression. Exact match to the reference scan
// (words resolved ascending; cross-word masks strictly upper-triangular).
__global__ __launch_bounds__(1024) void k_scan_out(const float* __restrict__ pred,
                                                   const int* __restrict__ sel,
                                                   const uint32_t* __restrict__ mask,
                                                   float* __restrict__ det,
                                                   float* __restrict__ keep_out) {
  int b = blockIdx.x;
  int tid = threadIdx.x;
  int lane = tid & 63, wv = tid >> 6;
  __shared__ uint32_t vbits[32];
  __shared__ uint32_t keepw[32];

  int n = sel[(size_t)b * TOPK + tid];
  const float4* rowv = (const float4*)(pred + ((size_t)b * NN + n) * NF);
  float4 r0 = rowv[0], r1 = rowv[1], r2 = rowv[2], r3 = rowv[3];
  float obj = r1.x, cls = r3.w;
  float score = __fmul_rn(cls, obj);
  bool valid = (obj > CONF) && (score > CONF);
  uint64_t bal = __ballot(valid);
  if (lane == 0) {
    vbits[2 * wv] = (uint32_t)bal;
    vbits[2 * wv + 1] = (uint32_t)(bal >> 32);
  }
  __syncthreads();

  if (tid < 32) {
    int l = tid;
    uint32_t kw = vbits[l];
    const uint4* mc = (const uint4*)(mask + (size_t)b * (32 * TOPK) + (size_t)l * TOPK);
    uint32_t cur[32], nxt[32];
    #pragma unroll
    for (int q = 0; q < 8; ++q) *(uint4*)&cur[4 * q] = mc[q];
    for (int w = 0; w < 32; ++w) {
      if (w < 31) {
        #pragma unroll
        for (int q = 0; q < 8; ++q) *(uint4*)&nxt[4 * q] = mc[(w + 1) * 8 + q];
      }
      // resolve intra-word (meaningful on lane w only; lanes<w have zero masks)
      uint32_t rw = kw;
      #pragma unroll
      for (int t = 0; t < 32; ++t)
        if ((rw >> t) & 1u) rw &= ~cur[t];
      uint32_t rf = __shfl(rw, w, 64);
      if (l == w) {
        kw = rf;
      } else {
        #pragma unroll
        for (int t = 0; t < 32; ++t)
          if ((rf >> t) & 1u) kw &= ~cur[t];
      }
      if (w < 31) {
        #pragma unroll
        for (int t = 0; t < 32; ++t) cur[t] = nxt[t];
      }
    }
    keepw[l] = kw;
  }
  __syncthreads();

  bool kept = (keepw[tid >> 5] >> (tid & 31)) & 1u;
  float m = kept ? 1.0f : 0.0f;
  float hw = __fmul_rn(r0.z, 0.5f), hh = __fmul_rn(r0.w, 0.5f);
  float4 o0 = make_float4(__fsub_rn(r0.x, hw) * m, __fsub_rn(r0.y, hh) * m,
                          __fadd_rn(r0.x, hw) * m, __fadd_rn(r0.y, hh) * m);
  float4 o1 = make_float4(score * m, r1.y * m, r1.z * m, r1.w * m);
  float4 o2 = make_float4(r2.x * m, r2.y * m, r2.z * m, r2.w * m);
  float4 o3 = make_float4(r3.x * m, r3.y * m, r3.z * m, 0.0f);
  float4* dst = (float4*)(det + ((size_t)b * TOPK + tid) * NF);
  dst[0] = o0; dst[1] = o1; dst[2] = o2; dst[3] = o3;
  keep_out[(size_t)b * TOPK + tid] = m;
}

extern "C" void kernel_launch(void* const* d_in, const int* in_sizes, int n_in,
                              void* d_out, int out_size, void* d_ws, size_t ws_size,
                              hipStream_t stream) {
  const float* pred = (const float*)d_in[0];
  float* det = (float*)d_out;
  float* keep = det + (size_t)NB * TOPK * NF;

  uint8_t* ws = (uint8_t*)d_ws;
  uint32_t* keys = (uint32_t*)ws;                                   // NB*NN u32
  int* sel = (int*)(ws + (size_t)NB * NN * 4);                      // NB*TOPK i32
  uint32_t* mask = (uint32_t*)(ws + (size_t)NB * NN * 4
                                  + (size_t)NB * TOPK * 4);         // NB*32*TOPK u32

  k_keys<<<(NB * NN + 255) / 256, 256, 0, stream>>>(pred, keys);
  k_select<<<NB, 1024, 0, stream>>>(keys, sel);
  dim3 gm(NB, 8);
  k_mask<<<gm, 1024, 0, stream>>>(pred, sel, mask);
  k_scan_out<<<NB, 1024, 0, stream>>>(pred, sel, mask, det, keep);
}

// Round 4
// 172.768 us; speedup vs baseline: 1.7889x; 1.0814x over previous
//
#include <hip/hip_runtime.h>
#include <stdint.h>

#define NB 32
#define NN 25200
#define NN4 6300          // NN/4, exact
#define TOPK 1024
#define NF 16
#define CONF 0.25f
#define IOU_T 0.45f
#define NBIN 4096
#define CAP 2048
#define KEY_BASE 0xBE800001u  // lowest possible valid key (score just above 0.25)

// monotone-ascending uint32 map of the reference's s = valid ? obj*cls : -1.0
__device__ __forceinline__ uint32_t score_key(float obj, float cls) {
  float score = __fmul_rn(cls, obj);
  bool valid = (obj > CONF) && (score > CONF);
  float s = valid ? score : -1.0f;
  uint32_t u = __float_as_uint(s);
  return (u & 0x80000000u) ? ~u : (u | 0x80000000u);
}

__device__ __forceinline__ uint64_t shfl_xor_u64(uint64_t v, int m) {
  uint32_t lo = __shfl_xor((uint32_t)v, m, 64);
  uint32_t hi = __shfl_xor((uint32_t)(v >> 32), m, 64);
  return ((uint64_t)hi << 32) | lo;
}

__global__ void k_keys(const float* __restrict__ pred, uint32_t* __restrict__ keys) {
  int g = blockIdx.x * blockDim.x + threadIdx.x;
  if (g >= NB * NN) return;
  const float* row = pred + (size_t)g * NF;
  keys[g] = score_key(row[4], row[15]);
}

// One block per image. Uniform 4096-bin histogram over the valid-key range ->
// parallel suffix-scan for the rank-1024 crossing bin -> compact bins >= b*
// (~1026 elements; CAP=2048, zero-padded) -> register bitonic sort of 2048
// descending on 64-bit key (key32<<32 | ~n, all distinct): j=1024 in-thread,
// j in {64..512} via LDS exchange (14 stages), j<=32 via shfl_xor (no LDS).
// Yields exact jax.lax.top_k order.
__global__ __launch_bounds__(1024) void k_select(const uint32_t* __restrict__ keys,
                                                 int* __restrict__ sel) {
  int b = blockIdx.x;
  int tid = threadIdx.x;
  int lane = tid & 63, wid = tid >> 6;
  const uint32_t* kb = keys + (size_t)b * NN;
  const uint4* kb4 = (const uint4*)kb;
  __shared__ uint32_t hist[NBIN];
  __shared__ uint64_t ent[CAP];
  __shared__ uint32_t wsum[16];
  __shared__ uint32_t sh_bin;
  __shared__ uint32_t sh_cnt;
  #pragma unroll
  for (int k = 0; k < 4; ++k) hist[tid + 1024 * k] = 0;
  ent[tid] = 0; ent[tid + 1024] = 0;
  if (tid == 0) { sh_cnt = 0; sh_bin = 0; }
  __syncthreads();

  // phase 1: histogram (valid keys only, ~2.5 per bin -> negligible conflicts)
  for (int i = tid; i < NN4; i += 1024) {
    uint4 k4 = kb4[i];
    uint32_t kv[4] = {k4.x, k4.y, k4.z, k4.w};
    #pragma unroll
    for (int c = 0; c < 4; ++c) {
      uint32_t key = kv[c];
      if (key >= KEY_BASE) {
        uint32_t bin = (key - KEY_BASE) >> 12;
        if (bin > NBIN - 1) bin = NBIN - 1;
        atomicAdd(&hist[bin], 1u);
      }
    }
  }
  __syncthreads();

  // phase 2: descending-bin cumulative via shfl scan; find crossing bin
  uint32_t h[4]; uint32_t s = 0;
  #pragma unroll
  for (int k = 0; k < 4; ++k) { h[k] = hist[NBIN - 1 - (4 * tid + k)]; s += h[k]; }
  uint32_t my = s;
  #pragma unroll
  for (int d = 1; d < 64; d <<= 1) {
    uint32_t v = __shfl_up(s, d, 64);
    if (lane >= d) s += v;
  }
  if (lane == 63) wsum[wid] = s;
  __syncthreads();
  uint32_t base = 0;
  for (int w = 0; w < wid; ++w) base += wsum[w];
  uint32_t cum = base + s - my;  // exclusive prefix (descending bins)
  #pragma unroll
  for (int k = 0; k < 4; ++k) {
    if (cum < TOPK && cum + h[k] >= TOPK) sh_bin = (uint32_t)(NBIN - 1 - (4 * tid + k));
    cum += h[k];
  }
  __syncthreads();
  uint32_t thr = KEY_BASE + (sh_bin << 12);

  // phase 3: compact everything in bins >= b* (contains all of top-1024)
  for (int i = tid; i < NN4; i += 1024) {
    uint4 k4 = kb4[i];
    uint32_t kv[4] = {k4.x, k4.y, k4.z, k4.w};
    #pragma unroll
    for (int c = 0; c < 4; ++c) {
      uint32_t key = kv[c];
      if (key >= thr) {
        uint32_t p = atomicAdd(&sh_cnt, 1u);
        if (p < CAP) ent[p] = ((uint64_t)key << 32) | (uint32_t)(~(uint32_t)(4 * i + c));
      }
    }
  }
  __syncthreads();

  // phase 4: register bitonic, 2048 descending, 2 elems/thread
  uint64_t v0 = ent[tid], v1 = ent[tid + 1024];
  for (unsigned kk = 2; kk <= CAP; kk <<= 1) {
    for (unsigned j = kk >> 1; j > 0; j >>= 1) {
      if (j == 1024) {
        uint64_t mx = v0 > v1 ? v0 : v1;
        uint64_t mn = v0 > v1 ? v1 : v0;
        v0 = mx; v1 = mn;  // desc=true for kk=2048
      } else if (j >= 64) {
        __syncthreads();
        ent[tid] = v0; ent[tid + 1024] = v1;
        __syncthreads();
        uint64_t p0 = ent[tid ^ j], p1 = ent[(tid ^ j) + 1024];
        bool low = ((tid & j) == 0);
        bool d0 = ((tid & kk) == 0);
        bool d1 = (((tid + 1024) & kk) == 0);
        v0 = (low != d0) ? (v0 < p0 ? v0 : p0) : (v0 > p0 ? v0 : p0);
        v1 = (low != d1) ? (v1 < p1 ? v1 : p1) : (v1 > p1 ? v1 : p1);
      } else {
        uint64_t p0 = shfl_xor_u64(v0, (int)j);
        uint64_t p1 = shfl_xor_u64(v1, (int)j);
        bool low = ((tid & j) == 0);
        bool d0 = ((tid & kk) == 0);
        bool d1 = (((tid + 1024) & kk) == 0);
        v0 = (low != d0) ? (v0 < p0 ? v0 : p0) : (v0 > p0 ? v0 : p0);
        v1 = (low != d1) ? (v1 < p1 ? v1 : p1) : (v1 > p1 ? v1 : p1);
      }
    }
  }
  uint32_t n = ~(uint32_t)(v0 & 0xFFFFFFFFu);
  if (n >= NN) n = 0;  // safety only
  sel[(size_t)b * TOPK + tid] = (int)n;
}

// grid (NB, 8): block handles 128 rows of one image's 1024x1024 IoU>thres
// bitmask (upper-triangular: bit j set only for j>i). Column-major layout
// mask[b][word][row]. Tiles with part < sblk are entirely j<i -> write zeros.
__global__ __launch_bounds__(1024) void k_mask(const float* __restrict__ pred,
                                               const int* __restrict__ sel,
                                               uint32_t* __restrict__ mask) {
  int b = blockIdx.x;
  int sblk = blockIdx.y;
  int tid = threadIdx.x;
  int r_local = tid & 127;
  int part = tid >> 7;
  int i = sblk * 128 + r_local;
  if (part < sblk) {  // wave-uniform: strictly-lower tile, all zero
    #pragma unroll
    for (int wN = 0; wN < 4; ++wN)
      mask[(size_t)b * (32 * TOPK) + (size_t)(part * 4 + wN) * TOPK + i] = 0u;
    // still must participate in barrier below
  }
  __shared__ float bx1[TOPK], by1[TOPK], bx2[TOPK], by2[TOPK], bar[TOPK];
  {
    int n = sel[(size_t)b * TOPK + tid];
    const float4* row = (const float4*)(pred + ((size_t)b * NN + n) * NF);
    float4 r0 = row[0];
    float hw = __fmul_rn(r0.z, 0.5f), hh = __fmul_rn(r0.w, 0.5f);
    float x1 = __fsub_rn(r0.x, hw), y1 = __fsub_rn(r0.y, hh);
    float x2 = __fadd_rn(r0.x, hw), y2 = __fadd_rn(r0.y, hh);
    bx1[tid] = x1; by1[tid] = y1; bx2[tid] = x2; by2[tid] = y2;
    bar[tid] = __fmul_rn(__fsub_rn(x2, x1), __fsub_rn(y2, y1));
  }
  __syncthreads();
  if (part < sblk) return;
  float x1i = bx1[i], y1i = by1[i], x2i = bx2[i], y2i = by2[i], ai = bar[i];
  int jbase = part * 128;
  for (int wN = 0; wN < 4; ++wN) {
    uint32_t word = 0;
    int j0 = jbase + wN * 32;
    #pragma unroll
    for (int t2 = 0; t2 < 32; ++t2) {
      int j = j0 + t2;
      float lx = fmaxf(x1i, bx1[j]);
      float ly = fmaxf(y1i, by1[j]);
      float rx = fminf(x2i, bx2[j]);
      float ry = fminf(y2i, by2[j]);
      float wd = fmaxf(__fsub_rn(rx, lx), 0.0f);
      float ht = fmaxf(__fsub_rn(ry, ly), 0.0f);
      float inter = __fmul_rn(wd, ht);
      float den = __fadd_rn(__fsub_rn(__fadd_rn(ai, bar[j]), inter), 1e-7f);
      float iou = __fdiv_rn(inter, den);
      uint32_t bit = ((iou > IOU_T) && (j > i)) ? 1u : 0u;
      word |= bit << t2;
    }
    mask[(size_t)b * (32 * TOPK) + (size_t)(part * 4 + wN) * TOPK + i] = word;
  }
}

// One block per image. Word-serial greedy scan: 32 outer iterations; lane l
// owns keep word l; register double-buffered mask loads overlap compute.
__global__ __launch_bounds__(1024) void k_scan_out(const float* __restrict__ pred,
                                                   const int* __restrict__ sel,
                                                   const uint32_t* __restrict__ mask,
                                                   float* __restrict__ det,
                                                   float* __restrict__ keep_out) {
  int b = blockIdx.x;
  int tid = threadIdx.x;
  int lane = tid & 63, wv = tid >> 6;
  __shared__ uint32_t vbits[32];
  __shared__ uint32_t keepw[32];

  int n = sel[(size_t)b * TOPK + tid];
  const float4* rowv = (const float4*)(pred + ((size_t)b * NN + n) * NF);
  float4 r0 = rowv[0], r1 = rowv[1], r2 = rowv[2], r3 = rowv[3];
  float obj = r1.x, cls = r3.w;
  float score = __fmul_rn(cls, obj);
  bool valid = (obj > CONF) && (score > CONF);
  uint64_t bal = __ballot(valid);
  if (lane == 0) {
    vbits[2 * wv] = (uint32_t)bal;
    vbits[2 * wv + 1] = (uint32_t)(bal >> 32);
  }
  __syncthreads();

  if (tid < 32) {
    int l = tid;
    uint32_t kw = vbits[l];
    const uint4* mc = (const uint4*)(mask + (size_t)b * (32 * TOPK) + (size_t)l * TOPK);
    uint32_t cur[32], nxt[32];
    #pragma unroll
    for (int q = 0; q < 8; ++q) *(uint4*)&cur[4 * q] = mc[q];
    for (int w = 0; w < 32; ++w) {
      if (w < 31) {
        #pragma unroll
        for (int q = 0; q < 8; ++q) *(uint4*)&nxt[4 * q] = mc[(w + 1) * 8 + q];
      }
      uint32_t rw = kw;
      #pragma unroll
      for (int t = 0; t < 32; ++t)
        if ((rw >> t) & 1u) rw &= ~cur[t];
      uint32_t rf = __shfl(rw, w, 64);
      if (l == w) {
        kw = rf;
      } else {
        #pragma unroll
        for (int t = 0; t < 32; ++t)
          if ((rf >> t) & 1u) kw &= ~cur[t];
      }
      if (w < 31) {
        #pragma unroll
        for (int t = 0; t < 32; ++t) cur[t] = nxt[t];
      }
    }
    keepw[l] = kw;
  }
  __syncthreads();

  bool kept = (keepw[tid >> 5] >> (tid & 31)) & 1u;
  float m = kept ? 1.0f : 0.0f;
  float hw = __fmul_rn(r0.z, 0.5f), hh = __fmul_rn(r0.w, 0.5f);
  float4 o0 = make_float4(__fsub_rn(r0.x, hw) * m, __fsub_rn(r0.y, hh) * m,
                          __fadd_rn(r0.x, hw) * m, __fadd_rn(r0.y, hh) * m);
  float4 o1 = make_float4(score * m, r1.y * m, r1.z * m, r1.w * m);
  float4 o2 = make_float4(r2.x * m, r2.y * m, r2.z * m, r2.w * m);
  float4 o3 = make_float4(r3.x * m, r3.y * m, r3.z * m, 0.0f);
  float4* dst = (float4*)(det + ((size_t)b * TOPK + tid) * NF);
  dst[0] = o0; dst[1] = o1; dst[2] = o2; dst[3] = o3;
  keep_out[(size_t)b * TOPK + tid] = m;
}

extern "C" void kernel_launch(void* const* d_in, const int* in_sizes, int n_in,
                              void* d_out, int out_size, void* d_ws, size_t ws_size,
                              hipStream_t stream) {
  const float* pred = (const float*)d_in[0];
  float* det = (float*)d_out;
  float* keep = det + (size_t)NB * TOPK * NF;

  uint8_t* ws = (uint8_t*)d_ws;
  uint32_t* keys = (uint32_t*)ws;                                   // NB*NN u32
  int* sel = (int*)(ws + (size_t)NB * NN * 4);                      // NB*TOPK i32
  uint32_t* mask = (uint32_t*)(ws + (size_t)NB * NN * 4
                                  + (size_t)NB * TOPK * 4);         // NB*32*TOPK u32

  k_keys<<<(NB * NN + 255) / 256, 256, 0, stream>>>(pred, keys);
  k_select<<<NB, 1024, 0, stream>>>(keys, sel);
  dim3 gm(NB, 8);
  k_mask<<<gm, 1024, 0, stream>>>(pred, sel, mask);
  k_scan_out<<<NB, 1024, 0, stream>>>(pred, sel, mask, det, keep);
}